// Round 7
// baseline (4459.915 us; speedup 1.0000x reference)
//
#include <hip/hip_runtime.h>
#include <math.h>

#define Nn 1024
#define Ee 4
#define Uu 32
#define BLOCK_ROWS 16  // 4 waves x 4 rows

// ---------------------------------------------------------------------------
// pre-kernel: grid (128, 5), block 256. blockIdx.y = e (0..3 edge types,
// 4 = residual W2/b2).
//   e<4 : hpre_t[b][e][u][n] = sum_f ann[b,n,f]*Wa[e,f,u] + ba[e,u]  (u-major!)
//   e==4: res[b][n][u]       = sum_f ann[b,n,f]*W2[f,u]  + b2[u]
// ---------------------------------------------------------------------------
template <int F, int FA>
__global__ __launch_bounds__(256) void pre_kernel(
    const float* __restrict__ annA, const float* __restrict__ annB,
    const float* __restrict__ Wa, const float* __restrict__ ba,
    const float* __restrict__ W2, const float* __restrict__ b2,
    float* __restrict__ hpre_t, float* __restrict__ res)
{
    const int e = blockIdx.y;            // 0..4
    __shared__ float wlds[F * Uu];
    __shared__ float blds[Uu];
    const int tid = threadIdx.x;
    const float* wsrc = (e < 4) ? (Wa + (size_t)e * F * Uu) : W2;
    const float* bsrc = (e < 4) ? (ba + (size_t)e * Uu) : b2;
    for (int i = tid; i < F * Uu; i += 256) wlds[i] = wsrc[i];
    if (tid < Uu) blds[tid] = bsrc[tid];
    __syncthreads();

    const int g = blockIdx.x * 256 + tid;   // flat row in [0, B*N)
    const int b = g >> 10;
    const int n = g & 1023;

    float4 a4[F / 4];
    {
        const float4* rA = (const float4*)(annA + (size_t)g * FA);
#pragma unroll
        for (int i = 0; i < FA / 4; ++i) a4[i] = rA[i];
        if constexpr (F > FA) {
            const float4* rB = (const float4*)(annB + (size_t)g * (F - FA));
#pragma unroll
            for (int i = 0; i < (F - FA) / 4; ++i) a4[FA / 4 + i] = rB[i];
        }
    }

    float4 acc[8];
    const float4* bb = (const float4*)blds;
#pragma unroll
    for (int uq = 0; uq < 8; ++uq) acc[uq] = bb[uq];
    const float4* w4 = (const float4*)wlds;
#pragma unroll
    for (int f4 = 0; f4 < F / 4; ++f4) {
        const float4 av = a4[f4];
#pragma unroll
        for (int c = 0; c < 4; ++c) {
            const float s = (c == 0) ? av.x : (c == 1) ? av.y : (c == 2) ? av.z : av.w;
#pragma unroll
            for (int uq = 0; uq < 8; ++uq) {
                const float4 w = w4[(f4 * 4 + c) * 8 + uq];  // uniform -> broadcast
                acc[uq].x = fmaf(s, w.x, acc[uq].x);
                acc[uq].y = fmaf(s, w.y, acc[uq].y);
                acc[uq].z = fmaf(s, w.z, acc[uq].z);
                acc[uq].w = fmaf(s, w.w, acc[uq].w);
            }
        }
    }
    if (e < 4) {
        float* dst = hpre_t + ((size_t)(b * 4 + e) * Uu) * Nn + n;  // [b][e][u][n]
#pragma unroll
        for (int uq = 0; uq < 8; ++uq) {
            dst[(uq * 4 + 0) * Nn] = acc[uq].x;
            dst[(uq * 4 + 1) * Nn] = acc[uq].y;
            dst[(uq * 4 + 2) * Nn] = acc[uq].z;
            dst[(uq * 4 + 3) * Nn] = acc[uq].w;
        }
    } else {
        float4* dst = (float4*)(res + (size_t)g * Uu);
#pragma unroll
        for (int uq = 0; uq < 8; ++uq) dst[uq] = acc[uq];
    }
}

// ---------------------------------------------------------------------------
// main kernel: out[b][n][u] = tanh( sum_e sum_m adj[b,e,n,m]*h_pre[b,e,m,u]
//                                   + res[b,n,u] )
// Distance-2 software pipeline, ALL register-staged (no global_load_lds, so
// ds_reads have no vmem dependence and barriers never force vmcnt(0)):
//   adj(t) -> one of 4 rotating reg buffers (av0..av3), issued at body t-2.
//   h(t)   -> parity reg pairs (hP0a/b even t, hP1a/b odd t), issued at t-2;
//             ds_written to hbuf[t&1] at body t (counted vmcnt, load landed).
// Body(t): ds_write h(t); issue h(t+2)+adj(t+2); lgkmcnt(0); raw s_barrier;
//          sched_barrier(0); compute(t) (ds_read hbuf + FMA with av[t%4]).
// Buffer-reuse race is safe: compute(t)'s ds_reads are waited by that wave's
// own lgkmcnt(0) at body t+1 BEFORE it signals barrier(t+1), and the next
// write to hbuf[t&1] happens only after barrier(t+1).
// 4 waves x 4 rows = 16 rows/block, grid 2048; lane = gu(u-octet) x ms(m-slot).
// VGPR ~ 4x16(av) + 32(acc) + 16(h) + addr ~= 120 -> launch_bounds(256,4),
// 4 blocks/CU, LDS 16 KiB.
// ---------------------------------------------------------------------------
__global__ __launch_bounds__(256, 4) void gcn_main_kernel(
    const float* __restrict__ adj,     // [B,E,N,N]
    const float* __restrict__ hpre_t,  // [B,E,U,N]
    const float* __restrict__ res,     // [B,N,U]
    float* __restrict__ out)           // [B,N,U]
{
    __shared__ float hbuf[2][Uu * 64];    // 2 x 8 KiB, [u][m] within chunk

    const int bid = blockIdx.x;                       // 2048 blocks
    const int swz = (bid & 7) * 256 + (bid >> 3);     // XCD-aware, bijective
    const int b = swz >> 6;                           // 64 blocks per b
    const int n0 = (swz & 63) * BLOCK_ROWS;
    const int tid = threadIdx.x;
    const int w = tid >> 6;       // wave 0..3
    const int lane = tid & 63;
    const int gu = lane >> 4;     // u-octet 0..3
    const int ms = lane & 15;     // m-slot 0..15
    const int wrow = n0 + w * 4;  // 4 rows per wave

    const float* adjb = adj + (size_t)b * Ee * Nn * Nn;
    const float* hpb  = hpre_t + (size_t)b * Ee * Uu * Nn;

    // h staging assignment: flat float4 index fi over chunk [32 u][16 quads]
    const int fi0 = tid, fi1 = tid + 256;
    const int su0 = fi0 >> 4, sm0 = fi0 & 15;
    const int su1 = fi1 >> 4, sm1 = fi1 & 15;

    float acc[4][8];
#pragma unroll
    for (int r = 0; r < 4; ++r)
#pragma unroll
        for (int j = 0; j < 8; ++j) acc[r][j] = 0.f;

    float4 av0[4], av1[4], av2[4], av3[4];
    float4 hP0a, hP0b, hP1a, hP1b;

#define ISSUE_H(HA, HB, T)                                                      \
    {                                                                           \
        const int e_ = (T) >> 4, c_ = (T) & 15;                                 \
        const float* hc_ = hpb + (size_t)e_ * Uu * Nn + c_ * 64;                \
        HA = *(const float4*)(hc_ + (size_t)su0 * Nn + sm0 * 4);                \
        HB = *(const float4*)(hc_ + (size_t)su1 * Nn + sm1 * 4);                \
    }

#define ISSUE_ADJ(AV, T)                                                        \
    {                                                                           \
        const int e_ = (T) >> 4, c_ = (T) & 15;                                 \
        const float* ap_ = adjb + ((size_t)e_ * Nn + wrow) * Nn + c_ * 64 + ms * 4; \
        AV[0] = *(const float4*)(ap_);                                          \
        AV[1] = *(const float4*)(ap_ + Nn);                                     \
        AV[2] = *(const float4*)(ap_ + 2 * Nn);                                 \
        AV[3] = *(const float4*)(ap_ + 3 * Nn);                                 \
    }

#define BODY(T, AVC, AVN, HA, HB)                                               \
    {                                                                           \
        const int t_ = (T);                                                     \
        float* hb = hbuf[t_ & 1];                                               \
        ((float4*)hb)[fi0] = HA;   /* counted vmcnt: h(t) landed 2 phases ago */\
        ((float4*)hb)[fi1] = HB;                                                \
        const int tn_ = t_ + 2;                                                 \
        if (tn_ < 64) {                                                         \
            ISSUE_H(HA, HB, tn_);                                               \
            ISSUE_ADJ(AVN, tn_);                                                \
        }                                                                       \
        asm volatile("s_waitcnt lgkmcnt(0)" ::: "memory");                      \
        __builtin_amdgcn_s_barrier();                                           \
        __builtin_amdgcn_sched_barrier(0);                                      \
        _Pragma("unroll")                                                       \
        for (int j = 0; j < 8; ++j) {                                           \
            const float4 hv = *(const float4*)(hb + (gu * 8 + j) * 64 + ms * 4); \
            _Pragma("unroll")                                                   \
            for (int r = 0; r < 4; ++r) {                                       \
                float t0 = fmaf(AVC[r].x, hv.x, acc[r][j]);                     \
                t0 = fmaf(AVC[r].y, hv.y, t0);                                  \
                t0 = fmaf(AVC[r].z, hv.z, t0);                                  \
                acc[r][j] = fmaf(AVC[r].w, hv.w, t0);                           \
            }                                                                   \
        }                                                                       \
    }

    // prologue: iters 0 and 1 in flight (h first, then adj, per buffer parity)
    ISSUE_H(hP0a, hP0b, 0);
    ISSUE_ADJ(av0, 0);
    ISSUE_H(hP1a, hP1b, 1);
    ISSUE_ADJ(av1, 1);

    for (int t = 0; t < 64; t += 4) {
        BODY(t + 0, av0, av2, hP0a, hP0b);
        BODY(t + 1, av1, av3, hP1a, hP1b);
        BODY(t + 2, av2, av0, hP0a, hP0b);
        BODY(t + 3, av3, av1, hP1a, hP1b);
    }

#undef BODY
#undef ISSUE_H
#undef ISSUE_ADJ

    // reduce partial sums across the 16 ms lanes (lane bits 0..3)
#pragma unroll
    for (int r = 0; r < 4; ++r)
#pragma unroll
        for (int j = 0; j < 8; ++j) {
            float v = acc[r][j];
            v += __shfl_xor(v, 1);
            v += __shfl_xor(v, 2);
            v += __shfl_xor(v, 4);
            v += __shfl_xor(v, 8);
            acc[r][j] = v;
        }

    // epilogue: lane ms==r writes row wrow+r (static acc indexing via unroll)
#pragma unroll
    for (int r = 0; r < 4; ++r) {
        if (ms == r) {
            const int n = wrow + r;
            const float* rp = res + ((size_t)b * Nn + n) * Uu + gu * 8;
            float* op = out + ((size_t)b * Nn + n) * Uu + gu * 8;
            const float4 r0 = *(const float4*)(rp);
            const float4 r1 = *(const float4*)(rp + 4);
            float4 o0, o1;
            o0.x = tanhf(acc[r][0] + r0.x);
            o0.y = tanhf(acc[r][1] + r0.y);
            o0.z = tanhf(acc[r][2] + r0.z);
            o0.w = tanhf(acc[r][3] + r0.w);
            o1.x = tanhf(acc[r][4] + r1.x);
            o1.y = tanhf(acc[r][5] + r1.y);
            o1.z = tanhf(acc[r][6] + r1.z);
            o1.w = tanhf(acc[r][7] + r1.w);
            *(float4*)(op) = o0;
            *(float4*)(op + 4) = o1;
        }
    }
}

extern "C" void kernel_launch(void* const* d_in, const int* in_sizes, int n_in,
                              void* d_out, int out_size, void* d_ws, size_t ws_size,
                              hipStream_t stream)
{
    const float* n_tensor = (const float*)d_in[0];  // [32,1024,32]
    const float* adj      = (const float*)d_in[1];  // [32,4,1024,1024]
    const float* W_adj0   = (const float*)d_in[2];  // [4,32,32]
    const float* b_adj0   = (const float*)d_in[3];  // [4,32]
    const float* W2_0     = (const float*)d_in[4];  // [32,32]
    const float* b2_0     = (const float*)d_in[5];  // [32]
    const float* W_adj1   = (const float*)d_in[6];  // [4,64,32]
    const float* b_adj1   = (const float*)d_in[7];  // [4,32]
    const float* W2_1     = (const float*)d_in[8];  // [64,32]
    const float* b2_1     = (const float*)d_in[9];  // [32]
    float* outp = (float*)d_out;

    float* ws   = (float*)d_ws;
    float* hpre = ws;                            // 16 MiB
    float* resb = ws + (size_t)4 * 1024 * 1024;  // 4 MiB
    float* h0   = ws + (size_t)5 * 1024 * 1024;  // 4 MiB

    dim3 pre_grid(128, 5);

    // layer 0 (F = 32)
    pre_kernel<32, 32><<<pre_grid, 256, 0, stream>>>(n_tensor, nullptr, W_adj0, b_adj0,
                                                     W2_0, b2_0, hpre, resb);
    gcn_main_kernel<<<2048, 256, 0, stream>>>(adj, hpre, resb, h0);

    // layer 1 (F = 64, ann = concat(n_tensor, h0))
    pre_kernel<64, 32><<<pre_grid, 256, 0, stream>>>(n_tensor, h0, W_adj1, b_adj1,
                                                     W2_1, b2_1, hpre, resb);
    gcn_main_kernel<<<2048, 256, 0, stream>>>(adj, hpre, resb, outp);
}

// Round 8
// 436.648 us; speedup vs baseline: 10.2140x; 10.2140x over previous
//
#include <hip/hip_runtime.h>
#include <math.h>

#define Nn 1024
#define Ee 4
#define Uu 32
#define BLOCK_ROWS 32  // 4 waves x 8 rows

// ---------------------------------------------------------------------------
// pre-kernel: grid (128, 5), block 256. blockIdx.y = e (0..3 edge types,
// 4 = residual W2/b2).
//   e<4 : hpre_t[b][e][u][n] = sum_f ann[b,n,f]*Wa[e,f,u] + ba[e,u]  (u-major!)
//   e==4: res[b][n][u]       = sum_f ann[b,n,f]*W2[f,u]  + b2[u]
// ---------------------------------------------------------------------------
template <int F, int FA>
__global__ __launch_bounds__(256) void pre_kernel(
    const float* __restrict__ annA, const float* __restrict__ annB,
    const float* __restrict__ Wa, const float* __restrict__ ba,
    const float* __restrict__ W2, const float* __restrict__ b2,
    float* __restrict__ hpre_t, float* __restrict__ res)
{
    const int e = blockIdx.y;            // 0..4
    __shared__ float wlds[F * Uu];
    __shared__ float blds[Uu];
    const int tid = threadIdx.x;
    const float* wsrc = (e < 4) ? (Wa + (size_t)e * F * Uu) : W2;
    const float* bsrc = (e < 4) ? (ba + (size_t)e * Uu) : b2;
    for (int i = tid; i < F * Uu; i += 256) wlds[i] = wsrc[i];
    if (tid < Uu) blds[tid] = bsrc[tid];
    __syncthreads();

    const int g = blockIdx.x * 256 + tid;   // flat row in [0, B*N)
    const int b = g >> 10;
    const int n = g & 1023;

    float4 a4[F / 4];
    {
        const float4* rA = (const float4*)(annA + (size_t)g * FA);
#pragma unroll
        for (int i = 0; i < FA / 4; ++i) a4[i] = rA[i];
        if constexpr (F > FA) {
            const float4* rB = (const float4*)(annB + (size_t)g * (F - FA));
#pragma unroll
            for (int i = 0; i < (F - FA) / 4; ++i) a4[FA / 4 + i] = rB[i];
        }
    }

    float4 acc[8];
    const float4* bb = (const float4*)blds;
#pragma unroll
    for (int uq = 0; uq < 8; ++uq) acc[uq] = bb[uq];
    const float4* w4 = (const float4*)wlds;
#pragma unroll
    for (int f4 = 0; f4 < F / 4; ++f4) {
        const float4 av = a4[f4];
#pragma unroll
        for (int c = 0; c < 4; ++c) {
            const float s = (c == 0) ? av.x : (c == 1) ? av.y : (c == 2) ? av.z : av.w;
#pragma unroll
            for (int uq = 0; uq < 8; ++uq) {
                const float4 w = w4[(f4 * 4 + c) * 8 + uq];  // uniform -> broadcast
                acc[uq].x = fmaf(s, w.x, acc[uq].x);
                acc[uq].y = fmaf(s, w.y, acc[uq].y);
                acc[uq].z = fmaf(s, w.z, acc[uq].z);
                acc[uq].w = fmaf(s, w.w, acc[uq].w);
            }
        }
    }
    if (e < 4) {
        float* dst = hpre_t + ((size_t)(b * 4 + e) * Uu) * Nn + n;  // [b][e][u][n]
#pragma unroll
        for (int uq = 0; uq < 8; ++uq) {
            dst[(uq * 4 + 0) * Nn] = acc[uq].x;
            dst[(uq * 4 + 1) * Nn] = acc[uq].y;
            dst[(uq * 4 + 2) * Nn] = acc[uq].z;
            dst[(uq * 4 + 3) * Nn] = acc[uq].w;
        }
    } else {
        float4* dst = (float4*)(res + (size_t)g * Uu);
#pragma unroll
        for (int uq = 0; uq < 8; ++uq) dst[uq] = acc[uq];
    }
}

// ---------------------------------------------------------------------------
// main kernel: out[b][n][u] = tanh( sum_e sum_m adj[b,e,n,m]*h_pre[b,e,m,u]
//                                   + res[b,n,u] )
// R2 skeleton (register-staged h + raw barrier), with ONE fix: the body
// issues ALL of t+1's loads (h first, then adj) BEFORE the ds_write of h(t).
// Auto-waitcnt then resolves:
//   ds_write h(t)   -> vmcnt(17)  (h(t) is the OLDEST outstanding)  [counted]
//   compute's FMA   -> vmcnt(10)  (adj(t) older than the 10 t+1 loads) [counted]
// So no vmcnt(0) drain in steady state; HBM latency hides under the previous
// compute phase + TLP (3 blocks/CU). No launch_bounds minimum (R6/R7 lesson:
// a forced VGPR squeeze serializes loads or spills).
// 4 waves x 8 rows = 32 rows/block, grid 1024; lane = gu(u-octet) x ms(m-slot).
// ---------------------------------------------------------------------------
__global__ __launch_bounds__(256) void gcn_main_kernel(
    const float* __restrict__ adj,     // [B,E,N,N]
    const float* __restrict__ hpre_t,  // [B,E,U,N]
    const float* __restrict__ res,     // [B,N,U]
    float* __restrict__ out)           // [B,N,U]
{
    __shared__ float hbuf[2][Uu * 64];    // 2 x 8 KiB, [u][m] within chunk

    const int bid = blockIdx.x;                       // 1024 blocks
    const int swz = (bid & 7) * 128 + (bid >> 3);     // XCD-aware, bijective
    const int b = swz >> 5;                           // 32 blocks per b
    const int n0 = (swz & 31) * BLOCK_ROWS;
    const int tid = threadIdx.x;
    const int w = tid >> 6;       // wave 0..3
    const int lane = tid & 63;
    const int gu = lane >> 4;     // u-octet 0..3
    const int ms = lane & 15;     // m-slot 0..15
    const int wrow = n0 + w * 8;  // 8 rows per wave

    const float* adjb = adj + (size_t)b * Ee * Nn * Nn;
    const float* hpb  = hpre_t + (size_t)b * Ee * Uu * Nn;

    // h staging assignment: flat float4 index fi over chunk [32 u][16 quads]
    const int fi0 = tid, fi1 = tid + 256;
    const int su0 = fi0 >> 4, sm0 = fi0 & 15;
    const int su1 = fi1 >> 4, sm1 = fi1 & 15;

    float acc[8][8];
#pragma unroll
    for (int r = 0; r < 8; ++r)
#pragma unroll
        for (int j = 0; j < 8; ++j) acc[r][j] = 0.f;

    float4 av0[8], av1[8];
    float4 hA0, hA1, hB0, hB1;

#define ISSUE_H(HA, HB, T)                                                      \
    {                                                                           \
        const int e_ = (T) >> 4, c_ = (T) & 15;                                 \
        const float* hc_ = hpb + (size_t)e_ * Uu * Nn + c_ * 64;                \
        HA = *(const float4*)(hc_ + (size_t)su0 * Nn + sm0 * 4);                \
        HB = *(const float4*)(hc_ + (size_t)su1 * Nn + sm1 * 4);                \
    }

#define ISSUE_ADJ(AV, T)                                                        \
    {                                                                           \
        const int e_ = (T) >> 4, c_ = (T) & 15;                                 \
        const float* ap_ = adjb + ((size_t)e_ * Nn + wrow) * Nn + c_ * 64 + ms * 4; \
        _Pragma("unroll")                                                       \
        for (int r = 0; r < 8; ++r) AV[r] = *(const float4*)(ap_ + (size_t)r * Nn); \
    }

    // Body(t): [issue h(t+1), adj(t+1)] [pin] [ds_write h(t) -- counted vmcnt]
    //          [lgkmcnt(0); s_barrier] [compute(t) -- counted vmcnt for adj(t)]
#define BODY(T, AVC, AVN, HCa, HCb, HNa, HNb)                                   \
    {                                                                           \
        const int t_ = (T);                                                     \
        const int tn_ = (t_ < 63) ? t_ + 1 : 63;                                \
        ISSUE_H(HNa, HNb, tn_);                                                 \
        ISSUE_ADJ(AVN, tn_);                                                    \
        __builtin_amdgcn_sched_barrier(0);  /* keep issues above the ds_write */\
        float* hb = hbuf[t_ & 1];                                               \
        ((float4*)hb)[fi0] = HCa;   /* waits vmcnt(17): h(t) oldest, counted */ \
        ((float4*)hb)[fi1] = HCb;                                               \
        asm volatile("s_waitcnt lgkmcnt(0)" ::: "memory");                      \
        __builtin_amdgcn_s_barrier();                                           \
        __builtin_amdgcn_sched_barrier(0);                                      \
        _Pragma("unroll")                                                       \
        for (int j = 0; j < 8; ++j) {                                           \
            const float4 hv = *(const float4*)(hb + (gu * 8 + j) * 64 + ms * 4); \
            _Pragma("unroll")                                                   \
            for (int r = 0; r < 8; ++r) {                                       \
                float t0 = fmaf(AVC[r].x, hv.x, acc[r][j]);                     \
                t0 = fmaf(AVC[r].y, hv.y, t0);                                  \
                t0 = fmaf(AVC[r].z, hv.z, t0);                                  \
                acc[r][j] = fmaf(AVC[r].w, hv.w, t0);                           \
            }                                                                   \
        }                                                                       \
    }

    // prologue: issue iter 0 (h first, then adj -- h must be oldest)
    ISSUE_H(hA0, hA1, 0);
    ISSUE_ADJ(av0, 0);

    for (int t = 0; t < 64; t += 2) {
        BODY(t + 0, av0, av1, hA0, hA1, hB0, hB1);
        BODY(t + 1, av1, av0, hB0, hB1, hA0, hA1);
    }

#undef BODY
#undef ISSUE_H
#undef ISSUE_ADJ

    // reduce partial sums across the 16 ms lanes (lane bits 0..3)
#pragma unroll
    for (int r = 0; r < 8; ++r)
#pragma unroll
        for (int j = 0; j < 8; ++j) {
            float v = acc[r][j];
            v += __shfl_xor(v, 1);
            v += __shfl_xor(v, 2);
            v += __shfl_xor(v, 4);
            v += __shfl_xor(v, 8);
            acc[r][j] = v;
        }

    // epilogue: lane ms==r writes row wrow+r (static acc indexing via unroll)
#pragma unroll
    for (int r = 0; r < 8; ++r) {
        if (ms == r) {
            const int n = wrow + r;
            const float* rp = res + ((size_t)b * Nn + n) * Uu + gu * 8;
            float* op = out + ((size_t)b * Nn + n) * Uu + gu * 8;
            const float4 r0 = *(const float4*)(rp);
            const float4 r1 = *(const float4*)(rp + 4);
            float4 o0, o1;
            o0.x = tanhf(acc[r][0] + r0.x);
            o0.y = tanhf(acc[r][1] + r0.y);
            o0.z = tanhf(acc[r][2] + r0.z);
            o0.w = tanhf(acc[r][3] + r0.w);
            o1.x = tanhf(acc[r][4] + r1.x);
            o1.y = tanhf(acc[r][5] + r1.y);
            o1.z = tanhf(acc[r][6] + r1.z);
            o1.w = tanhf(acc[r][7] + r1.w);
            *(float4*)(op) = o0;
            *(float4*)(op + 4) = o1;
        }
    }
}

extern "C" void kernel_launch(void* const* d_in, const int* in_sizes, int n_in,
                              void* d_out, int out_size, void* d_ws, size_t ws_size,
                              hipStream_t stream)
{
    const float* n_tensor = (const float*)d_in[0];  // [32,1024,32]
    const float* adj      = (const float*)d_in[1];  // [32,4,1024,1024]
    const float* W_adj0   = (const float*)d_in[2];  // [4,32,32]
    const float* b_adj0   = (const float*)d_in[3];  // [4,32]
    const float* W2_0     = (const float*)d_in[4];  // [32,32]
    const float* b2_0     = (const float*)d_in[5];  // [32]
    const float* W_adj1   = (const float*)d_in[6];  // [4,64,32]
    const float* b_adj1   = (const float*)d_in[7];  // [4,32]
    const float* W2_1     = (const float*)d_in[8];  // [64,32]
    const float* b2_1     = (const float*)d_in[9];  // [32]
    float* outp = (float*)d_out;

    float* ws   = (float*)d_ws;
    float* hpre = ws;                            // 16 MiB
    float* resb = ws + (size_t)4 * 1024 * 1024;  // 4 MiB
    float* h0   = ws + (size_t)5 * 1024 * 1024;  // 4 MiB

    dim3 pre_grid(128, 5);

    // layer 0 (F = 32)
    pre_kernel<32, 32><<<pre_grid, 256, 0, stream>>>(n_tensor, nullptr, W_adj0, b_adj0,
                                                     W2_0, b2_0, hpre, resb);
    gcn_main_kernel<<<1024, 256, 0, stream>>>(adj, hpre, resb, h0);

    // layer 1 (F = 64, ann = concat(n_tensor, h0))
    pre_kernel<64, 32><<<pre_grid, 256, 0, stream>>>(n_tensor, h0, W_adj1, b_adj1,
                                                     W2_1, b2_1, hpre, resb);
    gcn_main_kernel<<<1024, 256, 0, stream>>>(adj, hpre, resb, outp);
}